// Round 10
// baseline (111.059 us; speedup 1.0000x reference)
//
#include <hip/hip_runtime.h>
#include <hip/hip_bf16.h>

// T=6, B=2, Q=50 -> P=100 queries; N=8 targets; 72x72 -> 288x288 bilinear
// (align_corners=False, 4x => fixed weights); out C[B,Q,N] = 800 f32.
// R10: interpolation itself moved to MFMA: u[16px,16q] = W[16px,32cell] x
// pred[32cell,16q] per 32-px window (W = bilinear weights x -log2e, built once
// per block; ry-grouped row slabs make W block-constant; left/right edge W
// variants). Sigmoid+IoU on C-frags; dice via validated LDS+MFMA (32-px
// k-steps, 64B rows, XOR swizzle folded pre-swizzle per R6). qg=6 pad rows =
// ones -> tgt sums free (R9-validated). ws/reduce/final tail unchanged.

#define T_      6
#define P_      100
#define N_      8
#define HIN     72
#define SIN     (HIN*HIN)        // 5184
#define HOUT    288
#define S_OUT   (HOUT*HOUT)      // 82944
#define NQG     7                // query groups of 16 (100 -> 112 padded)
#define NCH     36               // ry(4) x grp(9); 8 same-ry rows per block
#define PART_F  320              // floats per partial slot
#define WS2_OFF (T_*NQG*NCH*PART_F)          // 483840
#define WLDS    3072             // per-wave LDS: actL 1K, actS 1K, g 1K
#define NLOG2E  (-1.4426950408889634f)

typedef __attribute__((ext_vector_type(8))) short short8;
typedef __attribute__((ext_vector_type(4))) float f32x4;

__device__ __forceinline__ unsigned cvt_pk_bf16(float lo, float hi) {
    unsigned r;
    asm("v_cvt_pk_bf16_f32 %0, %1, %2" : "=v"(r) : "v"(lo), "v"(hi));
    return r;
}
__device__ __forceinline__ short f2bf(float f) {
    union { __hip_bfloat16 h; short s; } u;
    u.h = __float2bfloat16(f);
    return u.s;
}

// ---------------------------------------------------------------------------
// Kernel 1: interp-MFMA + dice-MFMA. grid = T_*NQG*NCH, 256 threads (4 waves).
// ---------------------------------------------------------------------------
__global__ __launch_bounds__(256, 4) void mfma_partial(
    const float* __restrict__ predL, const float* __restrict__ predS,
    const float* __restrict__ tgt, float* __restrict__ ws)
{
    __shared__ __align__(16) char smem[4*WLDS + 512];
    float* iredN = (float*)(smem + 4*WLDS);        // [4][16]
    float* iredD = (float*)(smem + 4*WLDS + 256);  // [4][16]
    float (*cred)[64][8] = (float (*)[64][8])smem; // aliased over act area (end only)

    const int blk = blockIdx.x;                 // (t*NQG+qg)*NCH + ch
    const int t   = blk / (NQG*NCH);
    const int rem = blk % (NQG*NCH);
    const int qg  = rem / NCH;
    const int ch  = rem % NCH;
    const int ry  = ch / 9;                     // output-row phase (same W)
    const int grp = ch % 9;                     // row group

    const int lane = threadIdx.x & 63;
    const int wv   = threadIdx.x >> 6;
    char* actL = smem + wv*WLDS;
    char* actS = actL + 1024;
    char* gpl  = actL + 2048;

    const int q15 = lane & 15;                  // q col / px row / n col / arow
    const int kg  = lane >> 4;                  // k-group 0..3
    const int hi  = kg;                         // C-frag row group
    const int kga = kg & 1;                     // tap col-group (0..7 / 8..15)

    const int qv   = min(qg*16 + q15, P_-1);
    const int qoff = qv * SIN;
    const float* __restrict__ predLt = predL + (size_t)t*P_*SIN;
    const float* __restrict__ predSt = predS + (size_t)t*P_*SIN;
    const bool doStore = (qg < NQG-1) || (q15 < 4);

    // g-stage roles
    const int gn = lane >> 3, gf = lane & 7;
    const int gbase = (t*8 + gn) * S_OUT;

    // row-phase weights (block-constant), -log2e folded
    const float wt  = 0.375f + 0.5f*(float)(ry>>1) - 0.25f*(float)(ry&1);
    const float wtm = wt * NLOG2E, wbm = (1.0f - wt) * NLOG2E;

    // --- build W fragments: A[px=q15, k=8kg+j], k=(row<<4)|col of tap cell ---
    short8 WL0, WL1, WI0, WI1, WR0, WR1;
    {
        const int pat = q15 & 3, c4 = q15 >> 2;
        const float wcm0 = (pat==0)?0.375f:(pat==1)?0.125f:0.f;
        const float wcc0 = (pat==0)?0.625f:(pat==1)?0.875f:(pat==2)?0.875f:0.625f;
        const float wcp0 = (pat==2)?0.125f:(pat==3)?0.375f:0.f;
        auto build = [&](int off, int s, bool fL, bool fR) -> short8 {
            float m_cm = wcm0, m_cc = wcc0, m_cp = wcp0;
            if (fL && s==0 && c4==0) { m_cc += m_cm; m_cm = 0.f; }  // left col clamp
            if (fR && s==1 && c4==3) { m_cc += m_cp; m_cp = 0.f; }  // right col clamp
            const int cc = off + 4*s + c4;     // center-tap cell column
            short8 w;
#pragma unroll
            for (int j = 0; j < 8; j++) {
                const int k = 8*kg + j;
                const int r = k >> 4, c = k & 15;
                const float wc = (c==cc-1) ? m_cm : (c==cc) ? m_cc : (c==cc+1) ? m_cp : 0.f;
                w[j] = f2bf(wc * (r ? wbm : wtm));
            }
            return w;
        };
        WL0 = build(0,0,true,false);  WL1 = build(0,1,true,false);   // window 0 (base col 0)
        WI0 = build(1,0,false,false); WI1 = build(1,1,false,false);  // interior (base 8w-1)
        WR0 = build(8,0,false,true);  WR1 = build(8,1,false,true);   // window 8 (base 56)
    }

    // --- prefill g rows 8..15 (ones + zeros) and qg=6 pad act rows (ones) ---
    if (lane < 16) {
#pragma unroll
        for (int r = 8; r < 16; r++) {
            const unsigned val = (r==8) ? 0x3F803F80u : 0u;
            *(unsigned*)(gpl + ((r*64 + 4*lane) ^ ((r&3)<<4))) = val;
        }
    }
    if (qg == NQG-1 && lane < 16) {
#pragma unroll
        for (int r = 4; r < 16; r++) {
            const int o = (r*64 + 4*lane) ^ ((r&3)<<4);
            *(unsigned*)(actL + o) = 0x3F803F80u;
            *(unsigned*)(actS + o) = 0x3F803F80u;
        }
    }

    f32x4 accL = {0.f,0.f,0.f,0.f}, accS = {0.f,0.f,0.f,0.f};
    float iN = 0.f, iD = 0.f;

    for (int m = 0; m < 2; m++) {
        const int rowidx  = grp*8 + 2*wv + m;
        const int row_out = 4*rowidx + ry;
        int y0 = (ry < 2) ? rowidx-1 : rowidx;
        const int y1 = min(y0+1, HIN-1);
        y0 = max(y0, 0);
        const int yA     = ((kg < 2) ? y0 : y1) * HIN;   // tap row per k-group
        const int ibase  = qoff + yA + 8*kga;
        const int gibase = gbase + row_out*HOUT;

        auto window = [&](int c0c, int wpos, short8 W0, short8 W1) {
            // --- stage g (8 masks x 32 px -> bf16 tile rows n) ---
            {
                const int gi = gibase + 32*wpos + 4*gf;
                const float4 gv = *(const float4*)(tgt + gi);
                uint2 gp;
                gp.x = cvt_pk_bf16(gv.x, gv.y);
                gp.y = cvt_pk_bf16(gv.z, gv.w);
                *(uint2*)(gpl + ((gn*64 + 8*gf) ^ ((gn&3)<<4))) = gp;
            }
            // --- pred taps (B frag: pred[cell, q]) ---
            const int ib = ibase + c0c;
            const float4 tLa = *(const float4*)(predLt + ib);
            const float4 tLb = *(const float4*)(predLt + ib + 4);
            const float4 tSa = *(const float4*)(predSt + ib);
            const float4 tSb = *(const float4*)(predSt + ib + 4);
            short8 fBL, fBS;
            {
                unsigned* u = (unsigned*)&fBL;
                u[0]=cvt_pk_bf16(tLa.x,tLa.y); u[1]=cvt_pk_bf16(tLa.z,tLa.w);
                u[2]=cvt_pk_bf16(tLb.x,tLb.y); u[3]=cvt_pk_bf16(tLb.z,tLb.w);
                unsigned* v = (unsigned*)&fBS;
                v[0]=cvt_pk_bf16(tSa.x,tSa.y); v[1]=cvt_pk_bf16(tSa.z,tSa.w);
                v[2]=cvt_pk_bf16(tSb.x,tSb.y); v[3]=cvt_pk_bf16(tSb.z,tSb.w);
            }
            // --- interp MFMA: m = W x pred  (m = -log2e * u) ---
            const f32x4 z = {0.f,0.f,0.f,0.f};
            f32x4 mL0 = __builtin_amdgcn_mfma_f32_16x16x32_bf16(W0, fBL, z, 0,0,0);
            f32x4 mL1 = __builtin_amdgcn_mfma_f32_16x16x32_bf16(W1, fBL, z, 0,0,0);
            f32x4 mS0 = __builtin_amdgcn_mfma_f32_16x16x32_bf16(W0, fBS, z, 0,0,0);
            f32x4 mS1 = __builtin_amdgcn_mfma_f32_16x16x32_bf16(W1, fBS, z, 0,0,0);

            // --- sigmoid + conditioned IoU (lane holds q=lane&15) ---
            float aL[8], aS[8];
#pragma unroll
            for (int e = 0; e < 4; e++) {
                aL[e]   = __builtin_amdgcn_rcpf(1.f + __builtin_amdgcn_exp2f(mL0[e]));
                aL[4+e] = __builtin_amdgcn_rcpf(1.f + __builtin_amdgcn_exp2f(mL1[e]));
                aS[e]   = __builtin_amdgcn_rcpf(1.f + __builtin_amdgcn_exp2f(mS0[e]));
                aS[4+e] = __builtin_amdgcn_rcpf(1.f + __builtin_amdgcn_exp2f(mS1[e]));
                const float pl0 = (mL0[e] < 0.f) ? aL[e]   : 0.f;
                const float ps0 = (mS0[e] < 0.f) ? aS[e]   : 0.f;
                const float pl1 = (mL1[e] < 0.f) ? aL[4+e] : 0.f;
                const float ps1 = (mS1[e] < 0.f) ? aS[4+e] : 0.f;
                iN = fmaf(pl0, ps0, iN); iD += pl0;
                iN = fmaf(pl1, ps1, iN); iD += pl1;
            }
            // --- pack acts -> LDS (row q, px = s*16 + hi*4 + e) ---
            if (doStore) {
                const int sw = (q15&3)<<4;
                const int ab = q15*64 + 8*hi;
                uint2 w0, w1, v0, v1;
                w0.x = cvt_pk_bf16(aL[0],aL[1]); w0.y = cvt_pk_bf16(aL[2],aL[3]);
                w1.x = cvt_pk_bf16(aL[4],aL[5]); w1.y = cvt_pk_bf16(aL[6],aL[7]);
                v0.x = cvt_pk_bf16(aS[0],aS[1]); v0.y = cvt_pk_bf16(aS[2],aS[3]);
                v1.x = cvt_pk_bf16(aS[4],aS[5]); v1.y = cvt_pk_bf16(aS[6],aS[7]);
                *(uint2*)(actL + ((ab)    ^ sw)) = w0;
                *(uint2*)(actL + ((ab+32) ^ sw)) = w1;
                *(uint2*)(actS + ((ab)    ^ sw)) = v0;
                *(uint2*)(actS + ((ab+32) ^ sw)) = v1;
            }
            // --- dice MFMA (K=32, wave-private LDS: no barrier) ---
            const int foA = (q15*64 + 16*kg) ^ ((q15&3)<<4);
            short8 fAL = *(const short8*)(actL + foA);
            short8 fAS = *(const short8*)(actS + foA);
            short8 fBg = *(const short8*)(gpl  + foA);
            accL = __builtin_amdgcn_mfma_f32_16x16x32_bf16(fAL, fBg, accL, 0,0,0);
            accS = __builtin_amdgcn_mfma_f32_16x16x32_bf16(fAS, fBg, accS, 0,0,0);
        };

        window(0, 0, WL0, WL1);                       // left edge (base col 0)
        for (int wpos = 1; wpos < 8; wpos++)
            window(8*wpos - 1, wpos, WI0, WI1);       // interior
        window(56, 8, WR0, WR1);                      // right edge (base col 56)
    }

    // --- iou reduce across hi groups (lanes 0-15 hold per-q totals) ---
    iN += __shfl_xor(iN, 16); iN += __shfl_xor(iN, 32);
    iD += __shfl_xor(iD, 16); iD += __shfl_xor(iD, 32);

    __syncthreads();       // done with act LDS; cred aliases it now
#pragma unroll
    for (int e = 0; e < 4; e++) { cred[wv][lane][e] = accL[e]; cred[wv][lane][4+e] = accS[e]; }
    if (lane < 16) { iredN[wv*16 + lane] = iN; iredD[wv*16 + lane] = iD; }
    __syncthreads();

    float* wsb = ws + (size_t)blk * PART_F;
    if (threadIdx.x < 64) {
        const int l = threadIdx.x;
        const int colx = l & 15, rb = (l >> 4) * 4;
        if (colx < 9) {
#pragma unroll
            for (int e = 0; e < 4; e++) {
                const float sLv = cred[0][l][e]+cred[1][l][e]+cred[2][l][e]+cred[3][l][e];
                const float sSv = cred[0][l][4+e]+cred[1][l][4+e]+cred[2][l][4+e]+cred[3][l][4+e];
                wsb[colx*16 + rb + e] = sLv;
                wsb[144 + colx*16 + rb + e] = sSv;
            }
        }
    }
    if (threadIdx.x < 16) {
        wsb[288 + threadIdx.x] = iredN[threadIdx.x] + iredN[16+threadIdx.x]
                               + iredN[32+threadIdx.x] + iredN[48+threadIdx.x];
        wsb[304 + threadIdx.x] = iredD[threadIdx.x] + iredD[16+threadIdx.x]
                               + iredD[32+threadIdx.x] + iredD[48+threadIdx.x];
    }
}

// ---------------------------------------------------------------------------
// Kernel 2: reduce NCH chunk partials -> per-(t,qg) sums
// ---------------------------------------------------------------------------
__global__ __launch_bounds__(320) void reduce_kernel(float* __restrict__ ws)
{
    const int tq = blockIdx.x;               // t*NQG + qg
    for (int s = threadIdx.x; s < PART_F; s += 320) {
        float acc = 0.f;
        const float* base = ws + (size_t)tq*NCH*PART_F + s;
#pragma unroll 4
        for (int c = 0; c < NCH; c++) acc += base[(size_t)c*PART_F];
        ws[WS2_OFF + (size_t)tq*PART_F + s] = acc;
    }
}

// ---------------------------------------------------------------------------
// Kernel 3: finalize 800 outputs (gS from qg=6 pad ones-rows, row 4)
// ---------------------------------------------------------------------------
__global__ __launch_bounds__(64) void final_kernel(
    const float* __restrict__ pirL, const float* __restrict__ pirS,
    const int* __restrict__ refidx, const float* __restrict__ ws,
    float* __restrict__ out)
{
    const int gid = blockIdx.x*64 + threadIdx.x;
    if (gid >= P_*N_) return;
    const int p = gid >> 3, n = gid & 7;
    const int b = p / 50, qloc = p % 50;
    const int qg = p >> 4, row = p & 15;
    const int rg0 = refidx[0], rg1 = refidx[1] + 4;   // ref_indices[b] + b*(N/B)
    const bool isref = (n == rg0) || (n == rg1);

    float acc = 0.f;
    for (int t = 0; t < T_; t++) {
        const float* b2 = ws + WS2_OFF + (size_t)(t*NQG + qg)*PART_F;
        const float dL = b2[n*16 + row];
        const float sL = b2[128 + row];          // ones column (col 8)
        const float dS = b2[144 + n*16 + row];
        const float sS = b2[144 + 128 + row];
        const float iN = b2[288 + row];
        const float iD = b2[304 + row];
        // tgt sum from qg=6 pad ones-row (row 4 = first pad query)
        const float gS = ws[WS2_OFF + (size_t)(t*NQG + (NQG-1))*PART_F + n*16 + 4];

        const float diceL = (2.f*dL + 1.f) / (sL + gS + 1.f);
        const float diceS = (2.f*dS + 1.f) / (sS + gS + 1.f);
        const float iou   = (iN + 1.f) / (iD + 1.f);
        const int ib = ((t*2 + b)*50 + qloc)*2;
        const float l0 = pirL[ib], l1 = pirL[ib+1];
        const float m0 = pirS[ib], m1 = pirS[ib+1];
        const float pl = isref ? 1.f/(1.f + __expf(l1 - l0)) : 1.f/(1.f + __expf(l0 - l1));
        const float ps = isref ? 1.f/(1.f + __expf(m1 - m0)) : 1.f/(1.f + __expf(m0 - m1));
        acc += diceL + diceS + iou + pl + ps;
    }
    out[gid] = -acc * (1.0f / (float)T_);
}

extern "C" void kernel_launch(void* const* d_in, const int* in_sizes, int n_in,
                              void* d_out, int out_size, void* d_ws, size_t ws_size,
                              hipStream_t stream) {
    const float* predL = (const float*)d_in[0];   // [6,2,50,72,72]
    const float* predS = (const float*)d_in[1];   // [6,2,50,72,72]
    const float* pirL  = (const float*)d_in[2];   // [6,2,50,2]
    const float* pirS  = (const float*)d_in[3];   // [6,2,50,2]
    const float* tgt   = (const float*)d_in[4];   // [6,8,288,288]
    const int*   refix = (const int*)d_in[5];     // [2]
    float* ws  = (float*)d_ws;                    // ~497,280 floats (~1.99 MB)
    float* out = (float*)d_out;                   // 800 floats

    mfma_partial<<<T_*NQG*NCH, 256, 0, stream>>>(predL, predS, tgt, ws);
    reduce_kernel<<<T_*NQG, 320, 0, stream>>>(ws);
    final_kernel<<<(P_*N_ + 63)/64, 64, 0, stream>>>(pirL, pirS, refix, ws, out);
}

// Round 11
// 60.659 us; speedup vs baseline: 1.8309x; 1.8309x over previous
//
#include <hip/hip_runtime.h>
#include <hip/hip_bf16.h>

// T=6, B=2, Q=50 -> P=100 queries; N=8 targets; 72x72 -> 288x288 bilinear
// (align_corners=False, 4x => fixed weights); out C[B,Q,N] = 800 f32.
// R11 = R8 (best) + sched_barrier(0) pinning the 50-load batch per iter
// (forces all taps in flight -> one latency exposure) + R9's ones-pad trick
// (qg=6 pad act rows = bf16 ones, stores skipped -> dice row 4 = tgt sums;
// sumg_kernel deleted).

#define T_      6
#define P_      100
#define N_      8
#define HIN     72
#define SIN     (HIN*HIN)        // 5184
#define HOUT    288
#define S_OUT   (HOUT*HOUT)      // 82944
#define NQG     7                // query groups of 16 (100 -> 112 padded)
#define NCH     36               // pixel slabs per (t,qg): 2304 px each
#define PART_F  320              // floats per partial slot
#define WS2_OFF (T_*NQG*NCH*PART_F)          // 483840
#define NQUAD   (S_OUT/4)        // 20736 float4 per mask
#define WLDS    6144             // per-wave LDS: actL 2K, actS 2K, g 2K
#define NLOG2E  (-1.4426950408889634f)

typedef __attribute__((ext_vector_type(8))) short short8;
typedef __attribute__((ext_vector_type(4))) float f32x4;
typedef __attribute__((ext_vector_type(2))) float f32x2;

__device__ __forceinline__ unsigned cvt_pk_bf16(float lo, float hi) {
    unsigned r;
    asm("v_cvt_pk_bf16_f32 %0, %1, %2" : "=v"(r) : "v"(lo), "v"(hi));
    return r;
}

// a = sigmoid(u) where m = -log2e*u  =>  a = 1/(1+2^m)
__device__ __forceinline__ f32x2 sigm2m(f32x2 m) {
    f32x2 e;
    e.x = __builtin_amdgcn_exp2f(m.x);
    e.y = __builtin_amdgcn_exp2f(m.y);
    f32x2 d = e + 1.0f;
    f32x2 r;
    r.x = __builtin_amdgcn_rcpf(d.x);
    r.y = __builtin_amdgcn_rcpf(d.y);
    return r;
}

// ---------------------------------------------------------------------------
// Kernel 1: act pipeline + MFMA. grid = T_*NQG*NCH, 256 threads (4 waves).
// ---------------------------------------------------------------------------
__global__ __launch_bounds__(256, 4) void mfma_partial(
    const float* __restrict__ predL, const float* __restrict__ predS,
    const float* __restrict__ tgt, float* __restrict__ ws)
{
    __shared__ __align__(16) char smem[4*WLDS + 512];
    float* iredN = (float*)(smem + 4*WLDS);        // [4][16]
    float* iredD = (float*)(smem + 4*WLDS + 256);  // [4][16]
    float (*cred)[64][8] = (float (*)[64][8])smem; // aliased over act area (end only)

    const int blk = blockIdx.x;                 // (t*NQG+qg)*NCH + ch
    const int t   = blk / (NQG*NCH);
    const int rem = blk % (NQG*NCH);
    const int qg  = rem / NCH;
    const int ch  = rem % NCH;

    const int lane = threadIdx.x & 63;
    const int wv   = threadIdx.x >> 6;
    char* actL = smem + wv*WLDS;
    char* actS = actL + 2048;
    char* gpl  = actL + 4096;

    // act roles: hi = query subgroup (0..3), cell = 4-px cell (0..15)
    const int hi   = lane >> 4;
    const int cell = lane & 15;
    const float* __restrict__ pLb[4];
    const float* __restrict__ pSb[4];
    bool isPad[4];
#pragma unroll
    for (int r = 0; r < 4; r++) {
        const int qglob = qg*16 + r*4 + hi;
        isPad[r] = (qglob >= P_);
        const int qv = min(qglob, P_-1);
        pLb[r] = predL + ((size_t)t*P_ + qv)*SIN;
        pSb[r] = predS + ((size_t)t*P_ + qv)*SIN;
    }

    // g-stage roles: n = lane>>3, f = lane&7 (two float4 each: f and f+8)
    const int gn = lane >> 3, gf = lane & 7;
    const float4* __restrict__ gsrc = (const float4*)tgt + (size_t)(t*8 + gn)*NQUAD;
    const int gwoff = (gn*128 + 8*gf) ^ ((gn&7)<<4);

    // prefill B cols 8..15 (ones column + zeros), static across iters
    if (lane < 16) {
        *(uint2*)(gpl + ((8*128 + 8*lane) ^ 0)) = make_uint2(0x3F803F80u, 0x3F803F80u);
#pragma unroll
        for (int col = 9; col < 16; col++)
            *(uint2*)(gpl + ((col*128 + 8*lane) ^ ((col&7)<<4))) = make_uint2(0u, 0u);
    }
    // qg==6: prefill pad act rows (qloc 4..15) with bf16 ones; their stores are
    // skipped below, so these rows persist -> MFMA row = sum_px(g) (tgt sums).
    if (qg == NQG-1 && lane < 12) {
        const int qloc = 4 + lane;
#pragma unroll
        for (int c8 = 0; c8 < 8; c8++) {
            const int off = (qloc*128 + 16*c8) ^ ((qloc&7)<<4);
            *(uint4*)(actL + off) = make_uint4(0x3F803F80u,0x3F803F80u,0x3F803F80u,0x3F803F80u);
            *(uint4*)(actS + off) = make_uint4(0x3F803F80u,0x3F803F80u,0x3F803F80u,0x3F803F80u);
        }
    }

    f32x4 accL = {0.f,0.f,0.f,0.f}, accS = {0.f,0.f,0.f,0.f};
    f32x2 iN2[4], iD2[4];
#pragma unroll
    for (int r = 0; r < 4; r++) { iN2[r] = (f32x2)(0.f); iD2[r] = (f32x2)(0.f); }
    const int arow = lane & 15, kg = lane >> 4;   // MFMA fragment roles

    for (int it = 0; it < 9; it++) {
        const int px0 = ch*2304 + it*256 + wv*64;   // wave's 64-px chunk

        // --- geometry: shared by all 4 passes (depends only on cell) ---
        const unsigned p = px0 + 4*cell;
        const int row  = p / 288u;
        const int col4 = (p % 288u) >> 2;
        const int ry = row & 3, j = row >> 2;
        int y0 = (ry < 2) ? j-1 : j;
        int y1 = y0 + 1;
        y0 = max(y0, 0); y1 = min(y1, HIN-1);
        const float wt = 0.375f + 0.5f*(float)(ry>>1) - 0.25f*(float)(ry&1);
        const float wtm = wt * NLOG2E;              // fold -log2e into row weights
        const float wbm = (1.0f - wt) * NLOG2E;
        const int im1 = max(col4-1, 0), ip1 = min(col4+1, HIN-1);
        const int o0 = y0*HIN, o1 = y1*HIN;

        // --- LOAD BATCH: g chunk + all 4 passes' taps, then pin with
        //     sched_barrier(0) so nothing sinks: one latency exposure ---
        const int f4b = px0 >> 2;
        float4 ga = gsrc[f4b + gf];
        float4 gb = gsrc[f4b + gf + 8];

        f32x2 tap[4][6];   // [pass][tm,tc,tp,bm,bc,bp] ; .x = L, .y = S
#pragma unroll
        for (int r = 0; r < 4; r++) {
            const float* __restrict__ pLq = pLb[r];
            const float* __restrict__ pSq = pSb[r];
            tap[r][0].x = pLq[o0+im1];  tap[r][0].y = pSq[o0+im1];
            tap[r][1].x = pLq[o0+col4]; tap[r][1].y = pSq[o0+col4];
            tap[r][2].x = pLq[o0+ip1];  tap[r][2].y = pSq[o0+ip1];
            tap[r][3].x = pLq[o1+im1];  tap[r][3].y = pSq[o1+im1];
            tap[r][4].x = pLq[o1+col4]; tap[r][4].y = pSq[o1+col4];
            tap[r][5].x = pLq[o1+ip1];  tap[r][5].y = pSq[o1+ip1];
        }
        __builtin_amdgcn_sched_barrier(0);

        // --- stage g chunk (bf16, swizzled [n][k]) ---
        {
            uint2 pa, pb;
            pa.x = cvt_pk_bf16(ga.x, ga.y); pa.y = cvt_pk_bf16(ga.z, ga.w);
            pb.x = cvt_pk_bf16(gb.x, gb.y); pb.y = cvt_pk_bf16(gb.z, gb.w);
            *(uint2*)(gpl + gwoff) = pa;
            *(uint2*)(gpl + (gwoff ^ 64)) = pb;     // base bit6==0 pre-swz
        }

        // --- 4 passes x 4 queries, compute from registers ---
#pragma unroll
        for (int r = 0; r < 4; r++) {
            f32x2 vm = tap[r][0]*wtm + tap[r][3]*wbm;   // m-scale folded
            f32x2 vc = tap[r][1]*wtm + tap[r][4]*wbm;
            f32x2 vp = tap[r][2]*wtm + tap[r][5]*wbm;
            f32x2 m0 = vm*0.375f + vc*0.625f;
            f32x2 m1 = vm*0.125f + vc*0.875f;
            f32x2 m2 = vc*0.875f + vp*0.125f;
            f32x2 m3 = vc*0.625f + vp*0.375f;

            f32x2 a0 = sigm2m(m0), a1 = sigm2m(m1), a2 = sigm2m(m2), a3 = sigm2m(m3);

            // conditioned IoU: u>0 <=> m<0 ; packed accumulate
            f32x2 pl01, ps01, pl23, ps23;
            pl01.x = (m0.x < 0.f) ? a0.x : 0.f;  pl01.y = (m1.x < 0.f) ? a1.x : 0.f;
            ps01.x = (m0.y < 0.f) ? a0.y : 0.f;  ps01.y = (m1.y < 0.f) ? a1.y : 0.f;
            pl23.x = (m2.x < 0.f) ? a2.x : 0.f;  pl23.y = (m3.x < 0.f) ? a3.x : 0.f;
            ps23.x = (m2.y < 0.f) ? a2.y : 0.f;  ps23.y = (m3.y < 0.f) ? a3.y : 0.f;
            iN2[r] = pl01*ps01 + iN2[r];
            iN2[r] = pl23*ps23 + iN2[r];
            iD2[r] = iD2[r] + pl01 + pl23;

            if (!isPad[r]) {
                uint2 wl, wsv;
                wl.x  = cvt_pk_bf16(a0.x, a1.x); wl.y  = cvt_pk_bf16(a2.x, a3.x);
                wsv.x = cvt_pk_bf16(a0.y, a1.y); wsv.y = cvt_pk_bf16(a2.y, a3.y);
                const int qloc = r*4 + hi;
                const int aoff = (qloc*128 + 8*cell) ^ ((qloc&7)<<4);
                *(uint2*)(actL + aoff) = wl;
                *(uint2*)(actS + aoff) = wsv;
            }
        }

        // --- MFMA: 2 k-steps x 2 tensors (wave-private LDS: no barrier) ---
#pragma unroll
        for (int ks = 0; ks < 2; ks++) {
            const int fo = (arow*128 + 64*ks + 16*kg) ^ ((arow&7)<<4);
            short8 fAL = *(const short8*)(actL + fo);
            short8 fAS = *(const short8*)(actS + fo);
            short8 fB  = *(const short8*)(gpl  + fo);
            accL = __builtin_amdgcn_mfma_f32_16x16x32_bf16(fAL, fB, accL, 0, 0, 0);
            accS = __builtin_amdgcn_mfma_f32_16x16x32_bf16(fAS, fB, accS, 0, 0, 0);
        }
    }

    // --- iou reduce within 16-lane cell groups (cell==0 holds sum) ---
    float iN[4], iD[4];
#pragma unroll
    for (int r = 0; r < 4; r++) {
        iN[r] = iN2[r].x + iN2[r].y;
        iD[r] = iD2[r].x + iD2[r].y;
        iN[r] += __shfl_down(iN[r], 1); iN[r] += __shfl_down(iN[r], 2);
        iN[r] += __shfl_down(iN[r], 4); iN[r] += __shfl_down(iN[r], 8);
        iD[r] += __shfl_down(iD[r], 1); iD[r] += __shfl_down(iD[r], 2);
        iD[r] += __shfl_down(iD[r], 4); iD[r] += __shfl_down(iD[r], 8);
    }

    __syncthreads();       // done with act LDS; cred aliases it now
#pragma unroll
    for (int e = 0; e < 4; e++) { cred[wv][lane][e] = accL[e]; cred[wv][lane][4+e] = accS[e]; }
    if (cell == 0) {
#pragma unroll
        for (int r = 0; r < 4; r++) {
            iredN[wv*16 + r*4 + hi] = iN[r];
            iredD[wv*16 + r*4 + hi] = iD[r];
        }
    }
    __syncthreads();

    float* wsb = ws + (size_t)blk * PART_F;
    if (threadIdx.x < 64) {
        const int l = threadIdx.x;
        const int colx = l & 15, rb = (l >> 4) * 4;
        if (colx < 9) {
#pragma unroll
            for (int e = 0; e < 4; e++) {
                const float sLv = cred[0][l][e]+cred[1][l][e]+cred[2][l][e]+cred[3][l][e];
                const float sSv = cred[0][l][4+e]+cred[1][l][4+e]+cred[2][l][4+e]+cred[3][l][4+e];
                wsb[colx*16 + rb + e] = sLv;
                wsb[144 + colx*16 + rb + e] = sSv;
            }
        }
    }
    if (threadIdx.x < 16) {
        wsb[288 + threadIdx.x] = iredN[threadIdx.x] + iredN[16+threadIdx.x]
                               + iredN[32+threadIdx.x] + iredN[48+threadIdx.x];
        wsb[304 + threadIdx.x] = iredD[threadIdx.x] + iredD[16+threadIdx.x]
                               + iredD[32+threadIdx.x] + iredD[48+threadIdx.x];
    }
}

// ---------------------------------------------------------------------------
// Kernel 2: reduce NCH chunk partials -> per-(t,qg) sums
// ---------------------------------------------------------------------------
__global__ __launch_bounds__(320) void reduce_kernel(float* __restrict__ ws)
{
    const int tq = blockIdx.x;               // t*NQG + qg
    for (int s = threadIdx.x; s < PART_F; s += 320) {
        float acc = 0.f;
        const float* base = ws + (size_t)tq*NCH*PART_F + s;
#pragma unroll 4
        for (int c = 0; c < NCH; c++) acc += base[(size_t)c*PART_F];
        ws[WS2_OFF + (size_t)tq*PART_F + s] = acc;
    }
}

// ---------------------------------------------------------------------------
// Kernel 3: finalize 800 outputs (gS from qg=6 pad ones-rows, row 4)
// ---------------------------------------------------------------------------
__global__ __launch_bounds__(64) void final_kernel(
    const float* __restrict__ pirL, const float* __restrict__ pirS,
    const int* __restrict__ refidx, const float* __restrict__ ws,
    float* __restrict__ out)
{
    const int gid = blockIdx.x*64 + threadIdx.x;
    if (gid >= P_*N_) return;
    const int p = gid >> 3, n = gid & 7;
    const int b = p / 50, qloc = p % 50;
    const int qg = p >> 4, row = p & 15;
    const int rg0 = refidx[0], rg1 = refidx[1] + 4;   // ref_indices[b] + b*(N/B)
    const bool isref = (n == rg0) || (n == rg1);

    float acc = 0.f;
    for (int t = 0; t < T_; t++) {
        const float* b2 = ws + WS2_OFF + (size_t)(t*NQG + qg)*PART_F;
        const float dL = b2[n*16 + row];
        const float sL = b2[128 + row];          // ones column (col 8)
        const float dS = b2[144 + n*16 + row];
        const float sS = b2[144 + 128 + row];
        const float iN = b2[288 + row];
        const float iD = b2[304 + row];
        // tgt sum from qg=6 pad ones-row (row 4 = first pad query)
        const float gS = ws[WS2_OFF + (size_t)(t*NQG + (NQG-1))*PART_F + n*16 + 4];

        const float diceL = (2.f*dL + 1.f) / (sL + gS + 1.f);
        const float diceS = (2.f*dS + 1.f) / (sS + gS + 1.f);
        const float iou   = (iN + 1.f) / (iD + 1.f);
        const int ib = ((t*2 + b)*50 + qloc)*2;
        const float l0 = pirL[ib], l1 = pirL[ib+1];
        const float m0 = pirS[ib], m1 = pirS[ib+1];
        const float pl = isref ? 1.f/(1.f + __expf(l1 - l0)) : 1.f/(1.f + __expf(l0 - l1));
        const float ps = isref ? 1.f/(1.f + __expf(m1 - m0)) : 1.f/(1.f + __expf(m0 - m1));
        acc += diceL + diceS + iou + pl + ps;
    }
    out[gid] = -acc * (1.0f / (float)T_);
}

extern "C" void kernel_launch(void* const* d_in, const int* in_sizes, int n_in,
                              void* d_out, int out_size, void* d_ws, size_t ws_size,
                              hipStream_t stream) {
    const float* predL = (const float*)d_in[0];   // [6,2,50,72,72]
    const float* predS = (const float*)d_in[1];   // [6,2,50,72,72]
    const float* pirL  = (const float*)d_in[2];   // [6,2,50,2]
    const float* pirS  = (const float*)d_in[3];   // [6,2,50,2]
    const float* tgt   = (const float*)d_in[4];   // [6,8,288,288]
    const int*   refix = (const int*)d_in[5];     // [2]
    float* ws  = (float*)d_ws;                    // ~497,280 floats (~1.99 MB)
    float* out = (float*)d_out;                   // 800 floats

    mfma_partial<<<T_*NQG*NCH, 256, 0, stream>>>(predL, predS, tgt, ws);
    reduce_kernel<<<T_*NQG, 320, 0, stream>>>(ws);
    final_kernel<<<(P_*N_ + 63)/64, 64, 0, stream>>>(pirL, pirS, refix, ws, out);
}